// Round 2
// baseline (1212.637 us; speedup 1.0000x reference)
//
#include <hip/hip_runtime.h>
#include <hip/hip_bf16.h>
#include <math.h>

// Problem constants
#define LSEQ 128
#define BB 4
#define NTOK 512            // LSEQ*BB
#define ND 1024
#define NE 256
#define NPROJ 256
#define DEPTH 4
#define NV 128000
#define NC 5
#define C0 10000
#define NHEADROWS 128005    // NV + NC rows streamed (head = emb[:10000]+clusters, tail = emb[10000:])

#define TM 64
#define TN 64
#define TK 32

typedef __bf16 bf16x8 __attribute__((ext_vector_type(8)));
typedef float  f32x4  __attribute__((ext_vector_type(4)));

__device__ inline unsigned short f2bf_rne(float f) {
  unsigned int u = __float_as_uint(f);
  u += 0x7FFFu + ((u >> 16) & 1u);
  return (unsigned short)(u >> 16);
}

// ---------------------------------------------------------------------------
// Generic fp32 GEMM (kept for the small recurrent-path matmuls).
//   BT=false: B is (K,N) row-major.  BT=true: B is (N,K) row-major (B^T form).
// M,N multiples of 64; K multiple of 32. 256 threads, 4x4 per thread.
// ---------------------------------------------------------------------------
template<bool BT>
__global__ __launch_bounds__(256) void gemm_f32(
    const float* __restrict__ A, const float* __restrict__ Bm,
    float* __restrict__ C, int M, int N, int K, float alpha) {
  __shared__ float As[TM][TK + 1];
  __shared__ float Bs[TN][TK + 1];
  const int tid = threadIdx.x;
  const int tc = tid & 15, tr = tid >> 4;
  const int m0 = blockIdx.y * TM, n0 = blockIdx.x * TN;
  float acc[4][4] = {};
  for (int ks = 0; ks < K; ks += TK) {
#pragma unroll
    for (int i = 0; i < 2; ++i) {
      int idx = tid + 256 * i;
      int r = idx >> 3, kq = idx & 7;
      float4 v = *reinterpret_cast<const float4*>(A + (size_t)(m0 + r) * K + ks + kq * 4);
      As[r][kq * 4 + 0] = v.x; As[r][kq * 4 + 1] = v.y;
      As[r][kq * 4 + 2] = v.z; As[r][kq * 4 + 3] = v.w;
    }
    if (BT) {
#pragma unroll
      for (int i = 0; i < 2; ++i) {
        int idx = tid + 256 * i;
        int r = idx >> 3, kq = idx & 7;
        float4 v = *reinterpret_cast<const float4*>(Bm + (size_t)(n0 + r) * K + ks + kq * 4);
        Bs[r][kq * 4 + 0] = v.x; Bs[r][kq * 4 + 1] = v.y;
        Bs[r][kq * 4 + 2] = v.z; Bs[r][kq * 4 + 3] = v.w;
      }
    } else {
#pragma unroll
      for (int i = 0; i < 2; ++i) {
        int idx = tid + 256 * i;
        int kk = idx >> 4, nq = idx & 15;
        float4 v = *reinterpret_cast<const float4*>(Bm + (size_t)(ks + kk) * N + n0 + nq * 4);
        Bs[nq * 4 + 0][kk] = v.x; Bs[nq * 4 + 1][kk] = v.y;
        Bs[nq * 4 + 2][kk] = v.z; Bs[nq * 4 + 3][kk] = v.w;
      }
    }
    __syncthreads();
#pragma unroll
    for (int kk = 0; kk < TK; ++kk) {
      float a[4], b[4];
#pragma unroll
      for (int i = 0; i < 4; ++i) a[i] = As[tr * 4 + i][kk];
#pragma unroll
      for (int j = 0; j < 4; ++j) b[j] = Bs[tc * 4 + j][kk];
#pragma unroll
      for (int i = 0; i < 4; ++i)
#pragma unroll
        for (int j = 0; j < 4; ++j) acc[i][j] += a[i] * b[j];
    }
    __syncthreads();
  }
#pragma unroll
  for (int i = 0; i < 4; ++i)
#pragma unroll
    for (int j = 0; j < 4; ++j)
      C[(size_t)(m0 + tr * 4 + i) * N + n0 + tc * 4 + j] = alpha * acc[i][j];
}

// ---------------------------------------------------------------------------
// Embedding gather: Ex[n][e] = emb_weight[x[n]][e]
// ---------------------------------------------------------------------------
__global__ __launch_bounds__(256) void gather_emb(
    const int* __restrict__ x, const float* __restrict__ emb,
    float* __restrict__ Ex) {
  int n = blockIdx.x;
  int e = threadIdx.x;
  Ex[(size_t)n * NE + e] = emb[(size_t)x[n] * NE + e];
}

// ---------------------------------------------------------------------------
// SRU scan: 4096 threads, one per (b, d) channel; 128 sequential steps each.
// ---------------------------------------------------------------------------
__global__ __launch_bounds__(256) void sru_scan(
    const float* __restrict__ u, const float* __restrict__ h_in,
    const float* __restrict__ hidden, const float* __restrict__ wc,
    const float* __restrict__ bvec, float* __restrict__ h_out,
    float* __restrict__ out, int layer) {
  int idx = blockIdx.x * 256 + threadIdx.x;   // 0..4095
  int b = idx >> 10, d = idx & 1023;
  float c = hidden[layer * (BB * ND) + idx];
  float vf = wc[layer * 2 * ND + d];
  float vr = wc[layer * 2 * ND + ND + d];
  float bf = bvec[layer * 2 * ND + d] + (-3.0f);
  float br = bvec[layer * 2 * ND + ND + d];
  for (int t = 0; t < LSEQ; ++t) {
    size_t row = (size_t)t * BB + b;
    float u0 = u[row * (3 * ND) + d];
    float u1 = u[row * (3 * ND) + ND + d];
    float u2 = u[row * (3 * ND) + 2 * ND + d];
    float xt = h_in[row * ND + d];
    float f = 1.f / (1.f + expf(-(u1 + vf * c + bf)));
    float r = 1.f / (1.f + expf(-(u2 + vr * c + br)));
    c = f * c + (1.f - f) * u0;
    h_out[row * ND + d] = r * c + (1.f - r) * xt;
  }
  out[NTOK + layer * (BB * ND) + idx] = c;
}

// ---------------------------------------------------------------------------
// Fused head+tail logits via bf16 MFMA.
// Streams all 128005 W-rows (head emb[:10000] + 5 cluster rows at the end,
// tail emb[10000:]), computes logits = W @ proj_h^T in 128x128 tiles,
// exp()s and reduces into per-(token, segment) sums.
// seg 0..4 = tail clusters, 5 = head.
//
// fp32 -> bf16 (RNE) conversion is folded into LDS staging; A and B fragments
// use the identical lane->k mapping so any k-permutation cancels in A·B.
// C/D layout (verified m89/m91): col = lane&15, row = (lane>>4)*4 + reg.
// ---------------------------------------------------------------------------
#define HBM_TILE 128   // W rows per block
#define HBN_TILE 128   // tokens per block
#define HBK 64         // k per staging step
#define LDAP 72        // padded bf16 row stride (144 B = 9 * 16 B)

__device__ inline int seg_of(int v) {
  if (v < 10000)  return 5;
  if (v < 20000)  return 0;
  if (v < 40000)  return 1;
  if (v < 60000)  return 2;
  if (v < 100000) return 3;
  if (v < 128000) return 4;
  if (v < 128005) return 5;
  return -1;
}

__global__ __launch_bounds__(256) void head_tail_mfma(
    const float* __restrict__ emb, const float* __restrict__ cw,
    const float* __restrict__ ob, const float* __restrict__ cb,
    const float* __restrict__ ph, float* __restrict__ accum) {
  __shared__ unsigned short As[HBM_TILE][LDAP];  // W rows   (v  x k)
  __shared__ unsigned short Bs[HBN_TILE][LDAP];  // proj_h   (tok x k)
  __shared__ float red[HBN_TILE][6];

  const int tid = threadIdx.x;
  const int lane = tid & 63;
  const int w = tid >> 6;          // wave 0..3
  const int wr = w >> 1, wc = w & 1;
  const int lrow = lane & 15;
  const int lkg = lane >> 4;       // 0..3

  // bijective XCD-chunked swizzle (m204): grid is 4004 linear blocks,
  // each XCD gets a contiguous chunk -> 4 token-blocks of one row-tile
  // plus ~125 consecutive row-tiles share an L2.
  const int nwg = gridDim.x;               // 4004
  const int orig = blockIdx.x;
  const int xcd = orig & 7;
  const int i8 = orig >> 3;
  const int q = nwg >> 3, r8 = nwg & 7;
  const int swz = (xcd < r8 ? xcd * (q + 1) : r8 * (q + 1) + (xcd - r8) * q) + i8;
  const int v0 = (swz >> 2) * HBM_TILE;    // row tile   (1001 tiles)
  const int n0 = (swz & 3) * HBN_TILE;     // token tile (4 tiles)

  f32x4 acc[4][4] = {};

  for (int ks = 0; ks < NE; ks += HBK) {
    // stage A: 128 rows x 64 k, fp32 -> bf16
#pragma unroll
    for (int i = 0; i < 4; ++i) {
      int idx = tid + 256 * i;           // 0..1023
      int rr = idx >> 3, c8 = idx & 7;   // row, 8-col group
      int v = v0 + rr;
      float4 f0, f1;
      if (v < NV) {
        const float* p = emb + (size_t)v * NE + ks + c8 * 8;
        f0 = *reinterpret_cast<const float4*>(p);
        f1 = *reinterpret_cast<const float4*>(p + 4);
      } else if (v < NHEADROWS) {
        const float* p = cw + (size_t)(v - NV) * NE + ks + c8 * 8;
        f0 = *reinterpret_cast<const float4*>(p);
        f1 = *reinterpret_cast<const float4*>(p + 4);
      } else {
        f0 = make_float4(0.f, 0.f, 0.f, 0.f);
        f1 = f0;
      }
      unsigned short* dst = &As[rr][c8 * 8];
      dst[0] = f2bf_rne(f0.x); dst[1] = f2bf_rne(f0.y);
      dst[2] = f2bf_rne(f0.z); dst[3] = f2bf_rne(f0.w);
      dst[4] = f2bf_rne(f1.x); dst[5] = f2bf_rne(f1.y);
      dst[6] = f2bf_rne(f1.z); dst[7] = f2bf_rne(f1.w);
    }
    // stage B: 128 tokens x 64 k
#pragma unroll
    for (int i = 0; i < 4; ++i) {
      int idx = tid + 256 * i;
      int rr = idx >> 3, c8 = idx & 7;
      const float* p = ph + (size_t)(n0 + rr) * NE + ks + c8 * 8;
      float4 f0 = *reinterpret_cast<const float4*>(p);
      float4 f1 = *reinterpret_cast<const float4*>(p + 4);
      unsigned short* dst = &Bs[rr][c8 * 8];
      dst[0] = f2bf_rne(f0.x); dst[1] = f2bf_rne(f0.y);
      dst[2] = f2bf_rne(f0.z); dst[3] = f2bf_rne(f0.w);
      dst[4] = f2bf_rne(f1.x); dst[5] = f2bf_rne(f1.y);
      dst[6] = f2bf_rne(f1.z); dst[7] = f2bf_rne(f1.w);
    }
    __syncthreads();

#pragma unroll
    for (int kk2 = 0; kk2 < 2; ++kk2) {
      bf16x8 av[4], bv[4];
#pragma unroll
      for (int mi = 0; mi < 4; ++mi)
        av[mi] = *reinterpret_cast<const bf16x8*>(
            &As[wr * 64 + mi * 16 + lrow][kk2 * 32 + lkg * 8]);
#pragma unroll
      for (int ni = 0; ni < 4; ++ni)
        bv[ni] = *reinterpret_cast<const bf16x8*>(
            &Bs[wc * 64 + ni * 16 + lrow][kk2 * 32 + lkg * 8]);
#pragma unroll
      for (int mi = 0; mi < 4; ++mi)
#pragma unroll
        for (int ni = 0; ni < 4; ++ni)
          acc[mi][ni] = __builtin_amdgcn_mfma_f32_16x16x32_bf16(
              av[mi], bv[ni], acc[mi][ni], 0, 0, 0);
    }
    __syncthreads();
  }

  // ---- epilogue: exp + per-(token,seg) reduction ----
  for (int i = tid; i < HBN_TILE * 6; i += 256) red[i / 6][i % 6] = 0.f;
  __syncthreads();

#pragma unroll
  for (int ni = 0; ni < 4; ++ni) {
    int tok = wc * 64 + ni * 16 + lrow;  // block-local token
    float s[6] = {0.f, 0.f, 0.f, 0.f, 0.f, 0.f};
#pragma unroll
    for (int mi = 0; mi < 4; ++mi) {
#pragma unroll
      for (int j = 0; j < 4; ++j) {
        int v = v0 + wr * 64 + mi * 16 + lkg * 4 + j;
        int seg = seg_of(v);
        if (seg >= 0) {
          float bias = (v < NV) ? ob[v] : cb[v - NV];
          s[seg] += expf(acc[mi][ni][j] + bias);
        }
      }
    }
#pragma unroll
    for (int sg = 0; sg < 6; ++sg)
      if (s[sg] != 0.f) atomicAdd(&red[tok][sg], s[sg]);
  }
  __syncthreads();

  for (int i = tid; i < HBN_TILE * 6; i += 256) {
    float s = red[i / 6][i % 6];
    if (s != 0.f) atomicAdd(&accum[(size_t)(n0 + i / 6) * 6 + (i % 6)], s);
  }
}

// ---------------------------------------------------------------------------
// Final loss: one 64-lane wave per token.
// ---------------------------------------------------------------------------
__global__ __launch_bounds__(64) void loss_kernel(
    const float* __restrict__ ph, const float* __restrict__ emb,
    const float* __restrict__ cw, const float* __restrict__ ob,
    const float* __restrict__ cb, const int* __restrict__ y,
    const float* __restrict__ accum, float* __restrict__ out) {
  int n = blockIdx.x;
  int lane = threadIdx.x;
  int yv = y[n];
  int cluster = (yv >= 10000) + (yv >= 20000) + (yv >= 40000) + (yv >= 60000) + (yv >= 100000);
  int tci = min(max(cluster - 1, 0), NC - 1);
  int hy = min(yv, C0 - 1);
  float d1 = 0.f, d2 = 0.f, d3 = 0.f;
  for (int k = lane; k < NE; k += 64) {
    float p = ph[(size_t)n * NE + k];
    d1 += p * emb[(size_t)yv * NE + k];
    d2 += p * emb[(size_t)hy * NE + k];
    d3 += p * cw[(size_t)tci * NE + k];
  }
#pragma unroll
  for (int off = 32; off > 0; off >>= 1) {
    d1 += __shfl_down(d1, off);
    d2 += __shfl_down(d2, off);
    d3 += __shfl_down(d3, off);
  }
  if (lane == 0) {
    float logit_y = d1 + ob[yv];
    float head_tok = d2 + ob[hy];
    float clus = d3 + cb[tci];
    float head_lse = logf(accum[(size_t)n * 6 + 5]);
    float lp;
    if (cluster == 0) lp = head_tok - head_lse;
    else lp = (clus - head_lse) + (logit_y - logf(accum[(size_t)n * 6 + tci]));
    out[n] = -lp;
  }
}

// ---------------------------------------------------------------------------
// Launch
// ---------------------------------------------------------------------------
extern "C" void kernel_launch(void* const* d_in, const int* in_sizes, int n_in,
                              void* d_out, int out_size, void* d_ws, size_t ws_size,
                              hipStream_t stream) {
  const int*   x      = (const int*)d_in[0];
  const int*   y      = (const int*)d_in[1];
  const float* hidden = (const float*)d_in[2];
  const float* emb    = (const float*)d_in[3];
  const float* eproj  = (const float*)d_in[4];
  const float* obias  = (const float*)d_in[5];
  const float* cw     = (const float*)d_in[6];
  const float* cb     = (const float*)d_in[7];
  const float* Wp     = (const float*)d_in[8];
  const float* Wq     = (const float*)d_in[9];
  const float* wc     = (const float*)d_in[10];
  const float* bvec   = (const float*)d_in[11];
  float* out = (float*)d_out;

  // workspace layout (floats)
  float* ws = (float*)d_ws;
  float* Ex    = ws;                        // 512*256
  float* hA    = Ex + NTOK * NE;            // 512*1024
  float* hB    = hA + NTOK * ND;            // 512*1024
  float* P     = hB + NTOK * ND;            // 512*256
  float* U     = P + NTOK * NPROJ;          // 512*3072
  float* projh = U + NTOK * 3 * ND;         // 512*256
  float* accum = projh + NTOK * NE;         // 512*6

  hipMemsetAsync(accum, 0, (size_t)NTOK * 6 * sizeof(float), stream);

  // h = emb_weight[x] @ emb_proj.T * 32
  gather_emb<<<NTOK, NE, 0, stream>>>(x, emb, Ex);
  gemm_f32<true><<<dim3(ND / TN, NTOK / TM), 256, 0, stream>>>(
      Ex, eproj, hA, NTOK, ND, NE, 32.0f);

  float* hcur = hA;
  float* hnxt = hB;
  for (int l = 0; l < DEPTH; ++l) {
    gemm_f32<false><<<dim3(NPROJ / TN, NTOK / TM), 256, 0, stream>>>(
        hcur, Wp + (size_t)l * ND * NPROJ, P, NTOK, NPROJ, ND, 1.0f);
    gemm_f32<false><<<dim3(3 * ND / TN, NTOK / TM), 256, 0, stream>>>(
        P, Wq + (size_t)l * NPROJ * 3 * ND, U, NTOK, 3 * ND, NPROJ, 1.0f);
    sru_scan<<<16, 256, 0, stream>>>(U, hcur, hidden, wc, bvec, hnxt, out, l);
    float* t = hcur; hcur = hnxt; hnxt = t;
  }

  // proj_h = h @ emb_proj
  gemm_f32<false><<<dim3(NE / TN, NTOK / TM), 256, 0, stream>>>(
      hcur, eproj, projh, NTOK, NE, ND, 1.0f);

  // fused head+tail exp-sum accumulation (bf16 MFMA)
  int vtiles = (NHEADROWS + HBM_TILE - 1) / HBM_TILE;   // 1001
  head_tail_mfma<<<dim3((NTOK / HBN_TILE) * vtiles), 256, 0, stream>>>(
      emb, cw, obias, cb, projh, accum);

  // final per-token loss
  loss_kernel<<<NTOK, 64, 0, stream>>>(projh, emb, cw, obias, cb, y, accum, out);
}

// Round 6
// 648.162 us; speedup vs baseline: 1.8709x; 1.8709x over previous
//
#include <hip/hip_runtime.h>
#include <hip/hip_bf16.h>
#include <math.h>

#define LSEQ 128
#define BB 4
#define NTOK 512            // LSEQ*BB
#define ND 1024
#define NE 256
#define NPROJ 256
#define DEPTH 4
#define NV 128000
#define NC 5
#define C0 10000
#define NHEADROWS 128005
#define NROWS_PAD 128128    // padded to tile multiple

typedef unsigned short u16;
typedef __bf16 bf16x8 __attribute__((ext_vector_type(8)));
typedef float  f32x4  __attribute__((ext_vector_type(4)));
typedef u16    u16x8  __attribute__((ext_vector_type(8)));
typedef u16    u16x4  __attribute__((ext_vector_type(4)));

__device__ inline u16 f2bf_rne(float f) {
  unsigned int u = __float_as_uint(f);
  u += 0x7FFFu + ((u >> 16) & 1u);
  return (u16)(u >> 16);
}
// packed: low 16 = hi (truncated bf16), high 16 = lo (rne of residual)
__device__ inline unsigned int f2hilo_pk(float v) {
  unsigned int u = __float_as_uint(v);
  u16 h = (u16)(u >> 16);
  u16 l = f2bf_rne(v - __uint_as_float(u & 0xFFFF0000u));
  return (unsigned int)h | ((unsigned int)l << 16);
}

// ---------------------------------------------------------------------------
// conv_emb: emb[128000][256] + cw[5][256] fp32 -> Wb bf16 (rne)
// ---------------------------------------------------------------------------
__global__ __launch_bounds__(256) void conv_emb(
    const float* __restrict__ emb, const float* __restrict__ cw,
    u16* __restrict__ Wb) {
  const long NCH = (long)NHEADROWS * NE / 8;
  const long EMBN = (long)NV * NE;
  for (long i = (long)blockIdx.x * 256 + threadIdx.x; i < NCH; i += (long)gridDim.x * 256) {
    long e = i * 8;
    const float* src = (e < EMBN) ? emb + e : cw + (e - EMBN);
    float4 a = *reinterpret_cast<const float4*>(src);
    float4 b = *reinterpret_cast<const float4*>(src + 4);
    u16x8 o;
    o[0] = f2bf_rne(a.x); o[1] = f2bf_rne(a.y); o[2] = f2bf_rne(a.z); o[3] = f2bf_rne(a.w);
    o[4] = f2bf_rne(b.x); o[5] = f2bf_rne(b.y); o[6] = f2bf_rne(b.z); o[7] = f2bf_rne(b.w);
    *reinterpret_cast<u16x8*>(Wb + e) = o;
  }
}

// ---------------------------------------------------------------------------
// conv_hilo: elementwise fp32 -> (hi, lo) bf16 pair
// ---------------------------------------------------------------------------
__global__ __launch_bounds__(256) void conv_hilo(
    const float* __restrict__ src, u16* __restrict__ dh, u16* __restrict__ dl, long n4) {
  for (long i = (long)blockIdx.x * 256 + threadIdx.x; i < n4; i += (long)gridDim.x * 256) {
    float4 a = *reinterpret_cast<const float4*>(src + i * 4);
    unsigned int p0 = f2hilo_pk(a.x), p1 = f2hilo_pk(a.y);
    unsigned int p2 = f2hilo_pk(a.z), p3 = f2hilo_pk(a.w);
    u16x4 h, l;
    h[0] = (u16)p0; l[0] = (u16)(p0 >> 16);
    h[1] = (u16)p1; l[1] = (u16)(p1 >> 16);
    h[2] = (u16)p2; l[2] = (u16)(p2 >> 16);
    h[3] = (u16)p3; l[3] = (u16)(p3 >> 16);
    *reinterpret_cast<u16x4*>(dh + i * 4) = h;
    *reinterpret_cast<u16x4*>(dl + i * 4) = l;
  }
}

// ---------------------------------------------------------------------------
// tconv: src [K][N] fp32 (per-mat stride) -> dst [N][K] bf16 hi/lo (transpose)
// ---------------------------------------------------------------------------
__global__ __launch_bounds__(256) void tconv(
    const float* __restrict__ src, u16* __restrict__ dh, u16* __restrict__ dl,
    int K, int N, long sStride, long dStride) {
  __shared__ float t[32][33];
  const int mat = blockIdx.z;
  src += (long)mat * sStride; dh += (long)mat * dStride; dl += (long)mat * dStride;
  const int k0 = blockIdx.y * 32, n0 = blockIdx.x * 32;
  const int lr = threadIdx.x & 31, tr = threadIdx.x >> 5;
#pragma unroll
  for (int i = 0; i < 4; ++i)
    t[tr + i * 8][lr] = src[(size_t)(k0 + tr + i * 8) * N + n0 + lr];
  __syncthreads();
#pragma unroll
  for (int i = 0; i < 4; ++i) {
    int nl = tr + i * 8;
    unsigned int pk = f2hilo_pk(t[lr][nl]);
    size_t o = (size_t)(n0 + nl) * K + k0 + lr;
    dh[o] = (u16)pk; dl[o] = (u16)(pk >> 16);
  }
}

// ---------------------------------------------------------------------------
// gather_hilo: Ex = emb[x[n]] * 32 -> hi/lo
// ---------------------------------------------------------------------------
__global__ __launch_bounds__(256) void gather_hilo(
    const int* __restrict__ x, const float* __restrict__ emb,
    u16* __restrict__ Eh, u16* __restrict__ El) {
  int n = blockIdx.x, e = threadIdx.x;
  float v = emb[(size_t)x[n] * NE + e] * 32.0f;
  unsigned int pk = f2hilo_pk(v);
  Eh[(size_t)n * NE + e] = (u16)pk; El[(size_t)n * NE + e] = (u16)(pk >> 16);
}

// ---------------------------------------------------------------------------
// gemm3: C[M,N] = A @ B^T with hi/lo bf16 operands (3-term compensated MFMA).
// A*: [M][K] bf16 hi/lo.  B*: [N][K] bf16 hi/lo (B transposed, rows over K).
// Output flags: WF32 -> C fp32; WHILO -> Ch/Cl bf16 pair; WRNE -> Cr bf16 rne.
// 64x64 tile, 4 waves (2x2), each wave 32x32 via 2x2 16x16x32 frags.
// ---------------------------------------------------------------------------
#define GP 72
template<bool WF32, bool WHILO, bool WRNE>
__global__ __launch_bounds__(256) void gemm3(
    const u16* __restrict__ Ah, const u16* __restrict__ Al,
    const u16* __restrict__ Bh, const u16* __restrict__ Bl,
    float* __restrict__ C, u16* __restrict__ Ch, u16* __restrict__ Cl,
    u16* __restrict__ Cr, int M, int N, int K) {
  __shared__ u16 ash[64][GP], asl[64][GP], bsh[64][GP], bsl[64][GP];
  const int tid = threadIdx.x, lane = tid & 63, w = tid >> 6;
  const int wm = w >> 1, wn = w & 1, lrow = lane & 15, lkg = lane >> 4;
  const int m0 = blockIdx.y * 64, n0 = blockIdx.x * 64;
  f32x4 acc[2][2] = {};
  for (int ks = 0; ks < K; ks += 64) {
#pragma unroll
    for (int i = 0; i < 2; ++i) {
      int idx = tid + 256 * i, r = idx >> 3, c8 = (idx & 7) * 8;
      *reinterpret_cast<u16x8*>(&ash[r][c8]) = *reinterpret_cast<const u16x8*>(Ah + (size_t)(m0 + r) * K + ks + c8);
      *reinterpret_cast<u16x8*>(&asl[r][c8]) = *reinterpret_cast<const u16x8*>(Al + (size_t)(m0 + r) * K + ks + c8);
      *reinterpret_cast<u16x8*>(&bsh[r][c8]) = *reinterpret_cast<const u16x8*>(Bh + (size_t)(n0 + r) * K + ks + c8);
      *reinterpret_cast<u16x8*>(&bsl[r][c8]) = *reinterpret_cast<const u16x8*>(Bl + (size_t)(n0 + r) * K + ks + c8);
    }
    __syncthreads();
#pragma unroll
    for (int k2 = 0; k2 < 2; ++k2) {
      bf16x8 ah[2], al[2], bh[2], bl[2];
#pragma unroll
      for (int mi = 0; mi < 2; ++mi) {
        ah[mi] = *reinterpret_cast<const bf16x8*>(&ash[wm * 32 + mi * 16 + lrow][k2 * 32 + lkg * 8]);
        al[mi] = *reinterpret_cast<const bf16x8*>(&asl[wm * 32 + mi * 16 + lrow][k2 * 32 + lkg * 8]);
      }
#pragma unroll
      for (int ni = 0; ni < 2; ++ni) {
        bh[ni] = *reinterpret_cast<const bf16x8*>(&bsh[wn * 32 + ni * 16 + lrow][k2 * 32 + lkg * 8]);
        bl[ni] = *reinterpret_cast<const bf16x8*>(&bsl[wn * 32 + ni * 16 + lrow][k2 * 32 + lkg * 8]);
      }
#pragma unroll
      for (int mi = 0; mi < 2; ++mi)
#pragma unroll
        for (int ni = 0; ni < 2; ++ni) {
          acc[mi][ni] = __builtin_amdgcn_mfma_f32_16x16x32_bf16(ah[mi], bh[ni], acc[mi][ni], 0, 0, 0);
          acc[mi][ni] = __builtin_amdgcn_mfma_f32_16x16x32_bf16(ah[mi], bl[ni], acc[mi][ni], 0, 0, 0);
          acc[mi][ni] = __builtin_amdgcn_mfma_f32_16x16x32_bf16(al[mi], bh[ni], acc[mi][ni], 0, 0, 0);
        }
    }
    __syncthreads();
  }
#pragma unroll
  for (int mi = 0; mi < 2; ++mi)
#pragma unroll
    for (int ni = 0; ni < 2; ++ni)
#pragma unroll
      for (int j = 0; j < 4; ++j) {
        int row = m0 + wm * 32 + mi * 16 + lkg * 4 + j;
        int col = n0 + wn * 32 + ni * 16 + lrow;
        float v = acc[mi][ni][j];
        size_t o = (size_t)row * N + col;
        if (WF32) C[o] = v;
        if (WHILO) { unsigned int pk = f2hilo_pk(v); Ch[o] = (u16)pk; Cl[o] = (u16)(pk >> 16); }
        if (WRNE) Cr[o] = f2bf_rne(v);
      }
}

// ---------------------------------------------------------------------------
// SRU scan, unroll-4 load batching; writes h fp32 + hi/lo and c_final.
// ---------------------------------------------------------------------------
__global__ __launch_bounds__(256) void sru_scan(
    const float* __restrict__ u, const float* __restrict__ h_in,
    const float* __restrict__ hidden, const float* __restrict__ wcv,
    const float* __restrict__ bvec, float* __restrict__ h_out,
    u16* __restrict__ hOh, u16* __restrict__ hOl,
    float* __restrict__ out, int layer) {
  int idx = blockIdx.x * 256 + threadIdx.x;   // 0..4095
  int b = idx >> 10, d = idx & 1023;
  float c = hidden[layer * (BB * ND) + idx];
  float vf = wcv[layer * 2 * ND + d];
  float vr = wcv[layer * 2 * ND + ND + d];
  float bf = bvec[layer * 2 * ND + d] + (-3.0f);
  float br = bvec[layer * 2 * ND + ND + d];
  for (int t0 = 0; t0 < LSEQ; t0 += 4) {
    float u0[4], u1[4], u2[4], xt[4];
#pragma unroll
    for (int q = 0; q < 4; ++q) {
      size_t row = (size_t)(t0 + q) * BB + b;
      u0[q] = u[row * (3 * ND) + d];
      u1[q] = u[row * (3 * ND) + ND + d];
      u2[q] = u[row * (3 * ND) + 2 * ND + d];
      xt[q] = h_in[row * ND + d];
    }
#pragma unroll
    for (int q = 0; q < 4; ++q) {
      float f = 1.f / (1.f + __expf(-(u1[q] + vf * c + bf)));
      float r = 1.f / (1.f + __expf(-(u2[q] + vr * c + br)));
      c = f * c + (1.f - f) * u0[q];
      float h = r * c + (1.f - r) * xt[q];
      size_t row = (size_t)(t0 + q) * BB + b;
      h_out[row * ND + d] = h;
      unsigned int pk = f2hilo_pk(h);
      hOh[row * ND + d] = (u16)pk; hOl[row * ND + d] = (u16)(pk >> 16);
    }
  }
  out[NTOK + layer * (BB * ND) + idx] = c;
}

// ---------------------------------------------------------------------------
// head_tail: logits = Wb @ phb^T in 128x128 tiles (pre-converted bf16),
// exp + per-(token, segment) sums. seg 0..4 = tail clusters, 5 = head.
// ---------------------------------------------------------------------------
__device__ inline int seg_of(int v) {
  if (v < 10000)  return 5;
  if (v < 20000)  return 0;
  if (v < 40000)  return 1;
  if (v < 60000)  return 2;
  if (v < 100000) return 3;
  if (v < 128000) return 4;
  if (v < 128005) return 5;
  return -1;
}

__global__ __launch_bounds__(256) void head_tail(
    const u16* __restrict__ Wb, const float* __restrict__ ob,
    const float* __restrict__ cb, const u16* __restrict__ phb,
    float* __restrict__ accum) {
  __shared__ u16 As[128][GP];
  __shared__ u16 Bs[128][GP];
  __shared__ float red[128][6];
  const int tid = threadIdx.x, lane = tid & 63, w = tid >> 6;
  const int wr = w >> 1, wcq = w & 1, lrow = lane & 15, lkg = lane >> 4;

  // bijective XCD-chunked swizzle (m204)
  const int nwg = gridDim.x;
  const int orig = blockIdx.x;
  const int xcd = orig & 7, i8 = orig >> 3;
  const int q = nwg >> 3, r8 = nwg & 7;
  const int swz = (xcd < r8 ? xcd * (q + 1) : r8 * (q + 1) + (xcd - r8) * q) + i8;
  const int v0 = (swz >> 2) * 128;
  const int n0 = (swz & 3) * 128;

  f32x4 acc[4][4] = {};
  for (int ks = 0; ks < NE; ks += 64) {
#pragma unroll
    for (int i = 0; i < 4; ++i) {
      int idx = tid + 256 * i, rr = idx >> 3, c8 = (idx & 7) * 8;
      *reinterpret_cast<u16x8*>(&As[rr][c8]) =
          *reinterpret_cast<const u16x8*>(Wb + (size_t)(v0 + rr) * NE + ks + c8);
    }
#pragma unroll
    for (int i = 0; i < 4; ++i) {
      int idx = tid + 256 * i, rr = idx >> 3, c8 = (idx & 7) * 8;
      *reinterpret_cast<u16x8*>(&Bs[rr][c8]) =
          *reinterpret_cast<const u16x8*>(phb + (size_t)(n0 + rr) * NE + ks + c8);
    }
    __syncthreads();
#pragma unroll
    for (int k2 = 0; k2 < 2; ++k2) {
      bf16x8 av[4], bv[4];
#pragma unroll
      for (int mi = 0; mi < 4; ++mi)
        av[mi] = *reinterpret_cast<const bf16x8*>(&As[wr * 64 + mi * 16 + lrow][k2 * 32 + lkg * 8]);
#pragma unroll
      for (int ni = 0; ni < 4; ++ni)
        bv[ni] = *reinterpret_cast<const bf16x8*>(&Bs[wcq * 64 + ni * 16 + lrow][k2 * 32 + lkg * 8]);
#pragma unroll
      for (int mi = 0; mi < 4; ++mi)
#pragma unroll
        for (int ni = 0; ni < 4; ++ni)
          acc[mi][ni] = __builtin_amdgcn_mfma_f32_16x16x32_bf16(av[mi], bv[ni], acc[mi][ni], 0, 0, 0);
    }
    __syncthreads();
  }

  for (int i = tid; i < 128 * 6; i += 256) red[i / 6][i % 6] = 0.f;
  __syncthreads();
#pragma unroll
  for (int ni = 0; ni < 4; ++ni) {
    int tok = wcq * 64 + ni * 16 + lrow;
    float s[6] = {0.f, 0.f, 0.f, 0.f, 0.f, 0.f};
#pragma unroll
    for (int mi = 0; mi < 4; ++mi) {
#pragma unroll
      for (int j = 0; j < 4; ++j) {
        int v = v0 + wr * 64 + mi * 16 + lkg * 4 + j;
        int seg = seg_of(v);
        if (seg >= 0) {
          float bias = (v < NV) ? ob[v] : cb[v - NV];
          s[seg] += expf(acc[mi][ni][j] + bias);
        }
      }
    }
#pragma unroll
    for (int sg = 0; sg < 6; ++sg)
      if (s[sg] != 0.f) atomicAdd(&red[tok][sg], s[sg]);
  }
  __syncthreads();
  for (int i = tid; i < 128 * 6; i += 256) {
    float s = red[i / 6][i % 6];
    if (s != 0.f) atomicAdd(&accum[(size_t)(n0 + i / 6) * 6 + (i % 6)], s);
  }
}

// ---------------------------------------------------------------------------
// Final loss: one wave per token.
// ---------------------------------------------------------------------------
__global__ __launch_bounds__(64) void loss_kernel(
    const float* __restrict__ ph, const float* __restrict__ emb,
    const float* __restrict__ cw, const float* __restrict__ ob,
    const float* __restrict__ cb, const int* __restrict__ y,
    const float* __restrict__ accum, float* __restrict__ out) {
  int n = blockIdx.x, lane = threadIdx.x;
  int yv = y[n];
  int cluster = (yv >= 10000) + (yv >= 20000) + (yv >= 40000) + (yv >= 60000) + (yv >= 100000);
  int tci = min(max(cluster - 1, 0), NC - 1);
  int hy = min(yv, C0 - 1);
  float d1 = 0.f, d2 = 0.f, d3 = 0.f;
  for (int k = lane; k < NE; k += 64) {
    float p = ph[(size_t)n * NE + k];
    d1 += p * emb[(size_t)yv * NE + k];
    d2 += p * emb[(size_t)hy * NE + k];
    d3 += p * cw[(size_t)tci * NE + k];
  }
#pragma unroll
  for (int off = 32; off > 0; off >>= 1) {
    d1 += __shfl_down(d1, off);
    d2 += __shfl_down(d2, off);
    d3 += __shfl_down(d3, off);
  }
  if (lane == 0) {
    float logit_y = d1 + ob[yv];
    float head_tok = d2 + ob[hy];
    float clus = d3 + cb[tci];
    float head_lse = logf(accum[(size_t)n * 6 + 5]);
    float lp;
    if (cluster == 0) lp = head_tok - head_lse;
    else lp = (clus - head_lse) + (logit_y - logf(accum[(size_t)n * 6 + tci]));
    out[n] = -lp;
  }
}

// ---------------------------------------------------------------------------
extern "C" void kernel_launch(void* const* d_in, const int* in_sizes, int n_in,
                              void* d_out, int out_size, void* d_ws, size_t ws_size,
                              hipStream_t stream) {
  const int*   x      = (const int*)d_in[0];
  const int*   y      = (const int*)d_in[1];
  const float* hidden = (const float*)d_in[2];
  const float* emb    = (const float*)d_in[3];
  const float* eproj  = (const float*)d_in[4];
  const float* obias  = (const float*)d_in[5];
  const float* cwp    = (const float*)d_in[6];
  const float* cbp    = (const float*)d_in[7];
  const float* Wp     = (const float*)d_in[8];
  const float* Wq     = (const float*)d_in[9];
  const float* wcv    = (const float*)d_in[10];
  const float* bvec   = (const float*)d_in[11];
  float* out = (float*)d_out;

  char* p = (char*)d_ws;
  auto alloc = [&](size_t bytes) { char* r = p; p += (bytes + 255) & ~(size_t)255; return r; };
  u16*   WbB   = (u16*)alloc((size_t)NROWS_PAD * NE * 2);
  u16*   epH   = (u16*)alloc((size_t)ND * NE * 2);
  u16*   epL   = (u16*)alloc((size_t)ND * NE * 2);
  u16*   epTH  = (u16*)alloc((size_t)NE * ND * 2);
  u16*   epTL  = (u16*)alloc((size_t)NE * ND * 2);
  u16*   WpTH  = (u16*)alloc((size_t)DEPTH * NPROJ * ND * 2);
  u16*   WpTL  = (u16*)alloc((size_t)DEPTH * NPROJ * ND * 2);
  u16*   WqTH  = (u16*)alloc((size_t)DEPTH * 3 * ND * NPROJ * 2);
  u16*   WqTL  = (u16*)alloc((size_t)DEPTH * 3 * ND * NPROJ * 2);
  u16*   ExH   = (u16*)alloc((size_t)NTOK * NE * 2);
  u16*   ExL   = (u16*)alloc((size_t)NTOK * NE * 2);
  float* h0    = (float*)alloc((size_t)NTOK * ND * 4);
  float* h1    = (float*)alloc((size_t)NTOK * ND * 4);
  u16*   h0H   = (u16*)alloc((size_t)NTOK * ND * 2);
  u16*   h0L   = (u16*)alloc((size_t)NTOK * ND * 2);
  u16*   h1H   = (u16*)alloc((size_t)NTOK * ND * 2);
  u16*   h1L   = (u16*)alloc((size_t)NTOK * ND * 2);
  u16*   PH    = (u16*)alloc((size_t)NTOK * NPROJ * 2);
  u16*   PL    = (u16*)alloc((size_t)NTOK * NPROJ * 2);
  float* U     = (float*)alloc((size_t)NTOK * 3 * ND * 4);
  float* projh = (float*)alloc((size_t)NTOK * NE * 4);
  u16*   phb   = (u16*)alloc((size_t)NTOK * NE * 2);
  float* accum = (float*)alloc((size_t)NTOK * 6 * 4);

  (void)hipMemsetAsync(accum, 0, (size_t)NTOK * 6 * 4, stream);

  // weight prep (per call; graph-captured)
  conv_hilo<<<256, 256, 0, stream>>>(eproj, epH, epL, (long)ND * NE / 4);
  tconv<<<dim3(NE / 32, ND / 32, 1), 256, 0, stream>>>(eproj, epTH, epTL, ND, NE, 0, 0);
  tconv<<<dim3(NPROJ / 32, ND / 32, DEPTH), 256, 0, stream>>>(
      Wp, WpTH, WpTL, ND, NPROJ, (long)ND * NPROJ, (long)ND * NPROJ);
  tconv<<<dim3(3 * ND / 32, NPROJ / 32, DEPTH), 256, 0, stream>>>(
      Wq, WqTH, WqTL, NPROJ, 3 * ND, (long)NPROJ * 3 * ND, (long)NPROJ * 3 * ND);
  gather_hilo<<<NTOK, NE, 0, stream>>>(x, emb, ExH, ExL);

  // h0 = (emb[x]*32) @ eproj^T
  gemm3<true, true, false><<<dim3(ND / 64, NTOK / 64), 256, 0, stream>>>(
      ExH, ExL, epH, epL, h0, h0H, h0L, nullptr, NTOK, ND, NE);

  float* hcF = h0; u16* hcH = h0H; u16* hcL = h0L;
  float* hnF = h1; u16* hnH = h1H; u16* hnL = h1L;
  for (int l = 0; l < DEPTH; ++l) {
    gemm3<false, true, false><<<dim3(NPROJ / 64, NTOK / 64), 256, 0, stream>>>(
        hcH, hcL, WpTH + (size_t)l * NPROJ * ND, WpTL + (size_t)l * NPROJ * ND,
        nullptr, PH, PL, nullptr, NTOK, NPROJ, ND);
    gemm3<true, false, false><<<dim3(3 * ND / 64, NTOK / 64), 256, 0, stream>>>(
        PH, PL, WqTH + (size_t)l * 3 * ND * NPROJ, WqTL + (size_t)l * 3 * ND * NPROJ,
        U, nullptr, nullptr, nullptr, NTOK, 3 * ND, NPROJ);
    sru_scan<<<16, 256, 0, stream>>>(U, hcF, hidden, wcv, bvec, hnF, hnH, hnL, out, l);
    { float* t = hcF; hcF = hnF; hnF = t; }
    { u16* t = hcH; hcH = hnH; hnH = t; }
    { u16* t = hcL; hcL = hnL; hnL = t; }
  }

  // proj_h = h @ eproj  (fp32 for loss, rne-bf16 for head_tail)
  gemm3<true, false, true><<<dim3(NE / 64, NTOK / 64), 256, 0, stream>>>(
      hcH, hcL, epTH, epTL, projh, nullptr, nullptr, phb, NTOK, NE, ND);

  // emb -> bf16 right before head_tail for L2/L3 residency
  conv_emb<<<2048, 256, 0, stream>>>(emb, cwp, WbB);

  head_tail<<<dim3((NTOK / 128) * (NROWS_PAD / 128)), 256, 0, stream>>>(
      WbB, obias, cbp, phb, accum);

  loss_kernel<<<NTOK, 64, 0, stream>>>(projh, emb, cwp, obias, cbp, y, accum, out);
}

// Round 7
// 622.291 us; speedup vs baseline: 1.9487x; 1.0416x over previous
//
#include <hip/hip_runtime.h>
#include <hip/hip_bf16.h>
#include <math.h>

#define LSEQ 128
#define BB 4
#define NTOK 512            // LSEQ*BB
#define ND 1024
#define NE 256
#define NPROJ 256
#define DEPTH 4
#define NV 128000
#define NC 5
#define C0 10000
#define NHEADROWS 128005
#define NROWS_PAD 128128    // padded to tile multiple

typedef unsigned short u16;
typedef __bf16 bf16x8 __attribute__((ext_vector_type(8)));
typedef float  f32x4  __attribute__((ext_vector_type(4)));
typedef u16    u16x8  __attribute__((ext_vector_type(8)));
typedef u16    u16x4  __attribute__((ext_vector_type(4)));

__device__ inline u16 f2bf_rne(float f) {
  unsigned int u = __float_as_uint(f);
  u += 0x7FFFu + ((u >> 16) & 1u);
  return (u16)(u >> 16);
}
// packed: low 16 = hi (truncated bf16), high 16 = lo (rne of residual)
__device__ inline unsigned int f2hilo_pk(float v) {
  unsigned int u = __float_as_uint(v);
  u16 h = (u16)(u >> 16);
  u16 l = f2bf_rne(v - __uint_as_float(u & 0xFFFF0000u));
  return (unsigned int)h | ((unsigned int)l << 16);
}

// async global->LDS, 16B per lane; dest must be wave-uniform base (+lane*16)
__device__ __forceinline__ void gld16(const u16* g, u16* l) {
  __builtin_amdgcn_global_load_lds(
      (const __attribute__((address_space(1))) void*)g,
      (__attribute__((address_space(3))) void*)l, 16, 0, 0);
}

// ---------------------------------------------------------------------------
// conv_emb: emb[128000][256] + cw[5][256] fp32 -> Wb bf16 (rne)
// ---------------------------------------------------------------------------
__global__ __launch_bounds__(256) void conv_emb(
    const float* __restrict__ emb, const float* __restrict__ cw,
    u16* __restrict__ Wb) {
  const long NCH = (long)NHEADROWS * NE / 8;
  const long EMBN = (long)NV * NE;
  for (long i = (long)blockIdx.x * 256 + threadIdx.x; i < NCH; i += (long)gridDim.x * 256) {
    long e = i * 8;
    const float* src = (e < EMBN) ? emb + e : cw + (e - EMBN);
    float4 a = *reinterpret_cast<const float4*>(src);
    float4 b = *reinterpret_cast<const float4*>(src + 4);
    u16x8 o;
    o[0] = f2bf_rne(a.x); o[1] = f2bf_rne(a.y); o[2] = f2bf_rne(a.z); o[3] = f2bf_rne(a.w);
    o[4] = f2bf_rne(b.x); o[5] = f2bf_rne(b.y); o[6] = f2bf_rne(b.z); o[7] = f2bf_rne(b.w);
    *reinterpret_cast<u16x8*>(Wb + e) = o;
  }
}

// ---------------------------------------------------------------------------
// conv_hilo: elementwise fp32 -> (hi, lo) bf16 pair
// ---------------------------------------------------------------------------
__global__ __launch_bounds__(256) void conv_hilo(
    const float* __restrict__ src, u16* __restrict__ dh, u16* __restrict__ dl, long n4) {
  for (long i = (long)blockIdx.x * 256 + threadIdx.x; i < n4; i += (long)gridDim.x * 256) {
    float4 a = *reinterpret_cast<const float4*>(src + i * 4);
    unsigned int p0 = f2hilo_pk(a.x), p1 = f2hilo_pk(a.y);
    unsigned int p2 = f2hilo_pk(a.z), p3 = f2hilo_pk(a.w);
    u16x4 h, l;
    h[0] = (u16)p0; l[0] = (u16)(p0 >> 16);
    h[1] = (u16)p1; l[1] = (u16)(p1 >> 16);
    h[2] = (u16)p2; l[2] = (u16)(p2 >> 16);
    h[3] = (u16)p3; l[3] = (u16)(p3 >> 16);
    *reinterpret_cast<u16x4*>(dh + i * 4) = h;
    *reinterpret_cast<u16x4*>(dl + i * 4) = l;
  }
}

// ---------------------------------------------------------------------------
// tconv: src [K][N] fp32 (per-mat stride) -> dst [N][K] bf16 hi/lo (transpose)
// ---------------------------------------------------------------------------
__global__ __launch_bounds__(256) void tconv(
    const float* __restrict__ src, u16* __restrict__ dh, u16* __restrict__ dl,
    int K, int N, long sStride, long dStride) {
  __shared__ float t[32][33];
  const int mat = blockIdx.z;
  src += (long)mat * sStride; dh += (long)mat * dStride; dl += (long)mat * dStride;
  const int k0 = blockIdx.y * 32, n0 = blockIdx.x * 32;
  const int lr = threadIdx.x & 31, tr = threadIdx.x >> 5;
#pragma unroll
  for (int i = 0; i < 4; ++i)
    t[tr + i * 8][lr] = src[(size_t)(k0 + tr + i * 8) * N + n0 + lr];
  __syncthreads();
#pragma unroll
  for (int i = 0; i < 4; ++i) {
    int nl = tr + i * 8;
    unsigned int pk = f2hilo_pk(t[lr][nl]);
    size_t o = (size_t)(n0 + nl) * K + k0 + lr;
    dh[o] = (u16)pk; dl[o] = (u16)(pk >> 16);
  }
}

// ---------------------------------------------------------------------------
// gather_hilo: Ex = emb[x[n]] * 32 -> hi/lo
// ---------------------------------------------------------------------------
__global__ __launch_bounds__(256) void gather_hilo(
    const int* __restrict__ x, const float* __restrict__ emb,
    u16* __restrict__ Eh, u16* __restrict__ El) {
  int n = blockIdx.x, e = threadIdx.x;
  float v = emb[(size_t)x[n] * NE + e] * 32.0f;
  unsigned int pk = f2hilo_pk(v);
  Eh[(size_t)n * NE + e] = (u16)pk; El[(size_t)n * NE + e] = (u16)(pk >> 16);
}

// ---------------------------------------------------------------------------
// gemm3: C[M,N] = A @ B^T with hi/lo bf16 operands (3-term compensated MFMA).
// ---------------------------------------------------------------------------
#define GP 72
template<bool WF32, bool WHILO, bool WRNE>
__global__ __launch_bounds__(256) void gemm3(
    const u16* __restrict__ Ah, const u16* __restrict__ Al,
    const u16* __restrict__ Bh, const u16* __restrict__ Bl,
    float* __restrict__ C, u16* __restrict__ Ch, u16* __restrict__ Cl,
    u16* __restrict__ Cr, int M, int N, int K) {
  __shared__ u16 ash[64][GP], asl[64][GP], bsh[64][GP], bsl[64][GP];
  const int tid = threadIdx.x, lane = tid & 63, w = tid >> 6;
  const int wm = w >> 1, wn = w & 1, lrow = lane & 15, lkg = lane >> 4;
  const int m0 = blockIdx.y * 64, n0 = blockIdx.x * 64;
  f32x4 acc[2][2] = {};
  for (int ks = 0; ks < K; ks += 64) {
#pragma unroll
    for (int i = 0; i < 2; ++i) {
      int idx = tid + 256 * i, r = idx >> 3, c8 = (idx & 7) * 8;
      *reinterpret_cast<u16x8*>(&ash[r][c8]) = *reinterpret_cast<const u16x8*>(Ah + (size_t)(m0 + r) * K + ks + c8);
      *reinterpret_cast<u16x8*>(&asl[r][c8]) = *reinterpret_cast<const u16x8*>(Al + (size_t)(m0 + r) * K + ks + c8);
      *reinterpret_cast<u16x8*>(&bsh[r][c8]) = *reinterpret_cast<const u16x8*>(Bh + (size_t)(n0 + r) * K + ks + c8);
      *reinterpret_cast<u16x8*>(&bsl[r][c8]) = *reinterpret_cast<const u16x8*>(Bl + (size_t)(n0 + r) * K + ks + c8);
    }
    __syncthreads();
#pragma unroll
    for (int k2 = 0; k2 < 2; ++k2) {
      bf16x8 ah[2], al[2], bh[2], bl[2];
#pragma unroll
      for (int mi = 0; mi < 2; ++mi) {
        ah[mi] = *reinterpret_cast<const bf16x8*>(&ash[wm * 32 + mi * 16 + lrow][k2 * 32 + lkg * 8]);
        al[mi] = *reinterpret_cast<const bf16x8*>(&asl[wm * 32 + mi * 16 + lrow][k2 * 32 + lkg * 8]);
      }
#pragma unroll
      for (int ni = 0; ni < 2; ++ni) {
        bh[ni] = *reinterpret_cast<const bf16x8*>(&bsh[wn * 32 + ni * 16 + lrow][k2 * 32 + lkg * 8]);
        bl[ni] = *reinterpret_cast<const bf16x8*>(&bsl[wn * 32 + ni * 16 + lrow][k2 * 32 + lkg * 8]);
      }
#pragma unroll
      for (int mi = 0; mi < 2; ++mi)
#pragma unroll
        for (int ni = 0; ni < 2; ++ni) {
          acc[mi][ni] = __builtin_amdgcn_mfma_f32_16x16x32_bf16(ah[mi], bh[ni], acc[mi][ni], 0, 0, 0);
          acc[mi][ni] = __builtin_amdgcn_mfma_f32_16x16x32_bf16(ah[mi], bl[ni], acc[mi][ni], 0, 0, 0);
          acc[mi][ni] = __builtin_amdgcn_mfma_f32_16x16x32_bf16(al[mi], bh[ni], acc[mi][ni], 0, 0, 0);
        }
    }
    __syncthreads();
  }
#pragma unroll
  for (int mi = 0; mi < 2; ++mi)
#pragma unroll
    for (int ni = 0; ni < 2; ++ni)
#pragma unroll
      for (int j = 0; j < 4; ++j) {
        int row = m0 + wm * 32 + mi * 16 + lkg * 4 + j;
        int col = n0 + wn * 32 + ni * 16 + lrow;
        float v = acc[mi][ni][j];
        size_t o = (size_t)row * N + col;
        if (WF32) C[o] = v;
        if (WHILO) { unsigned int pk = f2hilo_pk(v); Ch[o] = (u16)pk; Cl[o] = (u16)(pk >> 16); }
        if (WRNE) Cr[o] = f2bf_rne(v);
      }
}

// ---------------------------------------------------------------------------
// SRU scan: 1-deep software-pipelined group loads (hide ~600cy load latency).
// ---------------------------------------------------------------------------
__device__ __forceinline__ void sru_load(
    const float* __restrict__ u, const float* __restrict__ h_in, int t0, int b, int d,
    float (&u0)[4], float (&u1)[4], float (&u2)[4], float (&xt)[4]) {
#pragma unroll
  for (int q = 0; q < 4; ++q) {
    size_t row = (size_t)(t0 + q) * BB + b;
    u0[q] = u[row * (3 * ND) + d];
    u1[q] = u[row * (3 * ND) + ND + d];
    u2[q] = u[row * (3 * ND) + 2 * ND + d];
    xt[q] = h_in[row * ND + d];
  }
}
__device__ __forceinline__ void sru_step(
    int t0, int b, int d, float& c, float vf, float vr, float bf, float br,
    const float (&u0)[4], const float (&u1)[4], const float (&u2)[4], const float (&xt)[4],
    float* __restrict__ h_out, u16* __restrict__ hOh, u16* __restrict__ hOl) {
#pragma unroll
  for (int q = 0; q < 4; ++q) {
    float f = 1.f / (1.f + __expf(-(u1[q] + vf * c + bf)));
    float r = 1.f / (1.f + __expf(-(u2[q] + vr * c + br)));
    c = f * c + (1.f - f) * u0[q];
    float h = r * c + (1.f - r) * xt[q];
    size_t row = (size_t)(t0 + q) * BB + b;
    h_out[row * ND + d] = h;
    unsigned int pk = f2hilo_pk(h);
    hOh[row * ND + d] = (u16)pk; hOl[row * ND + d] = (u16)(pk >> 16);
  }
}

__global__ __launch_bounds__(256) void sru_scan(
    const float* __restrict__ u, const float* __restrict__ h_in,
    const float* __restrict__ hidden, const float* __restrict__ wcv,
    const float* __restrict__ bvec, float* __restrict__ h_out,
    u16* __restrict__ hOh, u16* __restrict__ hOl,
    float* __restrict__ out, int layer) {
  int idx = blockIdx.x * 256 + threadIdx.x;   // 0..4095
  int b = idx >> 10, d = idx & 1023;
  float c = hidden[layer * (BB * ND) + idx];
  float vf = wcv[layer * 2 * ND + d];
  float vr = wcv[layer * 2 * ND + ND + d];
  float bf = bvec[layer * 2 * ND + d] + (-3.0f);
  float br = bvec[layer * 2 * ND + ND + d];
  float A0[4], A1[4], A2[4], A3[4], B0[4], B1[4], B2[4], B3[4];
  sru_load(u, h_in, 0, b, d, A0, A1, A2, A3);
  for (int t0 = 0; t0 < LSEQ; t0 += 8) {
    sru_load(u, h_in, t0 + 4, b, d, B0, B1, B2, B3);
    sru_step(t0, b, d, c, vf, vr, bf, br, A0, A1, A2, A3, h_out, hOh, hOl);
    if (t0 + 8 < LSEQ) sru_load(u, h_in, t0 + 8, b, d, A0, A1, A2, A3);
    sru_step(t0 + 4, b, d, c, vf, vr, bf, br, B0, B1, B2, B3, h_out, hOh, hOl);
  }
  out[NTOK + layer * (BB * ND) + idx] = c;
}

// ---------------------------------------------------------------------------
// head_tail v2: global_load_lds staging (linear dest + inverse-swizzled source),
// XOR-swizzled ds_read, double-buffered LDS, __expf + uniform-seg epilogue.
// ---------------------------------------------------------------------------
__device__ inline int seg_of(int v) {
  if (v < 10000)  return 5;
  if (v < 20000)  return 0;
  if (v < 40000)  return 1;
  if (v < 60000)  return 2;
  if (v < 100000) return 3;
  if (v < 128000) return 4;
  if (v < 128005) return 5;
  return -1;
}

__global__ __launch_bounds__(256) void head_tail(
    const u16* __restrict__ Wb, const float* __restrict__ ob,
    const float* __restrict__ cb, const u16* __restrict__ phb,
    float* __restrict__ accum) {
  __shared__ u16 As[2][128][64];
  __shared__ u16 Bs[2][128][64];
  __shared__ float red[128][6];
  const int tid = threadIdx.x, lane = tid & 63, w = tid >> 6;
  const int wr = w >> 1, wcq = w & 1, lrow = lane & 15, lkg = lane >> 4;

  // bijective XCD-chunked swizzle (m204)
  const int nwg = gridDim.x;
  const int orig = blockIdx.x;
  const int xcd = orig & 7, i8 = orig >> 3;
  const int q8 = nwg >> 3, r8 = nwg & 7;
  const int swz = (xcd < r8 ? xcd * (q8 + 1) : r8 * (q8 + 1) + (xcd - r8) * q8) + i8;
  const int v0 = (swz >> 2) * 128;
  const int n0 = (swz & 3) * 128;

  // staging descriptors: dest chunk c = tid + 256*i (linear); source chunk
  // pre-swizzled so LDS holds content at (row, q^ (row&7)) [T21 both-sides]
  int srow[4], scol[4];
#pragma unroll
  for (int i = 0; i < 4; ++i) {
    int cch = tid + 256 * i;
    srow[i] = cch >> 3;
    scol[i] = ((cch & 7) ^ ((cch >> 3) & 7)) * 8;
  }
  const u16* gA = Wb  + (size_t)v0 * NE;
  const u16* gB = phb + (size_t)n0 * NE;
  const int dchunk = w * 64;  // wave-uniform dest chunk base

  f32x4 acc[4][4] = {};

  auto stage = [&](int buf, int ks) {
#pragma unroll
    for (int i = 0; i < 4; ++i) {
      gld16(gA + (size_t)srow[i] * NE + ks + scol[i],
            &As[buf][0][0] + (size_t)(dchunk + 256 * i) * 8);
      gld16(gB + (size_t)srow[i] * NE + ks + scol[i],
            &Bs[buf][0][0] + (size_t)(dchunk + 256 * i) * 8);
    }
  };

  stage(0, 0);
  __syncthreads();
#pragma unroll
  for (int t = 0; t < 4; ++t) {
    if (t < 3) stage((t + 1) & 1, (t + 1) * 64);
    const int buf = t & 1;
#pragma unroll
    for (int k2 = 0; k2 < 2; ++k2) {
      bf16x8 av[4], bv[4];
      const int qc = k2 * 4 + lkg;
#pragma unroll
      for (int mi = 0; mi < 4; ++mi) {
        int R = wr * 64 + mi * 16 + lrow;
        av[mi] = *reinterpret_cast<const bf16x8*>(&As[buf][R][(qc ^ (R & 7)) * 8]);
      }
#pragma unroll
      for (int ni = 0; ni < 4; ++ni) {
        int R = wcq * 64 + ni * 16 + lrow;
        bv[ni] = *reinterpret_cast<const bf16x8*>(&Bs[buf][R][(qc ^ (R & 7)) * 8]);
      }
#pragma unroll
      for (int mi = 0; mi < 4; ++mi)
#pragma unroll
        for (int ni = 0; ni < 4; ++ni)
          acc[mi][ni] = __builtin_amdgcn_mfma_f32_16x16x32_bf16(av[mi], bv[ni], acc[mi][ni], 0, 0, 0);
    }
    __syncthreads();
  }

  // epilogue: __expf + wave-uniform segment per 16-row span
  for (int i = tid; i < 128 * 6; i += 256) (&red[0][0])[i] = 0.f;
  __syncthreads();
#pragma unroll
  for (int mi = 0; mi < 4; ++mi) {
    const int vbase = v0 + wr * 64 + mi * 16;
    const int seg = seg_of(vbase);   // 16-span is one segment (cutoffs % 16 == 0)
    if (seg < 0) continue;
    float bj[4]; bool ok[4];
#pragma unroll
    for (int j = 0; j < 4; ++j) {
      int v = vbase + lkg * 4 + j;
      ok[j] = (v < NHEADROWS);
      bj[j] = ok[j] ? ((v < NV) ? ob[v] : cb[v - NV]) : 0.f;
    }
#pragma unroll
    for (int ni = 0; ni < 4; ++ni) {
      int tok = wcq * 64 + ni * 16 + lrow;
      float s = 0.f;
#pragma unroll
      for (int j = 0; j < 4; ++j) {
        float e = __expf(acc[mi][ni][j] + bj[j]);
        s += ok[j] ? e : 0.f;
      }
      atomicAdd(&red[tok][seg], s);
    }
  }
  __syncthreads();
  for (int i = tid; i < 128 * 6; i += 256) {
    float s = (&red[0][0])[i];
    if (s != 0.f) atomicAdd(&accum[(size_t)(n0 + i / 6) * 6 + (i % 6)], s);
  }
}

// ---------------------------------------------------------------------------
// Final loss: one wave per token.
// ---------------------------------------------------------------------------
__global__ __launch_bounds__(64) void loss_kernel(
    const float* __restrict__ ph, const float* __restrict__ emb,
    const float* __restrict__ cw, const float* __restrict__ ob,
    const float* __restrict__ cb, const int* __restrict__ y,
    const float* __restrict__ accum, float* __restrict__ out) {
  int n = blockIdx.x, lane = threadIdx.x;
  int yv = y[n];
  int cluster = (yv >= 10000) + (yv >= 20000) + (yv >= 40000) + (yv >= 60000) + (yv >= 100000);
  int tci = min(max(cluster - 1, 0), NC - 1);
  int hy = min(yv, C0 - 1);
  float d1 = 0.f, d2 = 0.f, d3 = 0.f;
  for (int k = lane; k < NE; k += 64) {
    float p = ph[(size_t)n * NE + k];
    d1 += p * emb[(size_t)yv * NE + k];
    d2 += p * emb[(size_t)hy * NE + k];
    d3 += p * cw[(size_t)tci * NE + k];
  }
#pragma unroll
  for (int off = 32; off > 0; off >>= 1) {
    d1 += __shfl_down(d1, off);
    d2 += __shfl_down(d2, off);
    d3 += __shfl_down(d3, off);
  }
  if (lane == 0) {
    float logit_y = d1 + ob[yv];
    float head_tok = d2 + ob[hy];
    float clus = d3 + cb[tci];
    float head_lse = logf(accum[(size_t)n * 6 + 5]);
    float lp;
    if (cluster == 0) lp = head_tok - head_lse;
    else lp = (clus - head_lse) + (logit_y - logf(accum[(size_t)n * 6 + tci]));
    out[n] = -lp;
  }
}

// ---------------------------------------------------------------------------
extern "C" void kernel_launch(void* const* d_in, const int* in_sizes, int n_in,
                              void* d_out, int out_size, void* d_ws, size_t ws_size,
                              hipStream_t stream) {
  const int*   x      = (const int*)d_in[0];
  const int*   y      = (const int*)d_in[1];
  const float* hidden = (const float*)d_in[2];
  const float* emb    = (const float*)d_in[3];
  const float* eproj  = (const float*)d_in[4];
  const float* obias  = (const float*)d_in[5];
  const float* cwp    = (const float*)d_in[6];
  const float* cbp    = (const float*)d_in[7];
  const float* Wp     = (const float*)d_in[8];
  const float* Wq     = (const float*)d_in[9];
  const float* wcv    = (const float*)d_in[10];
  const float* bvec   = (const float*)d_in[11];
  float* out = (float*)d_out;

  char* p = (char*)d_ws;
  auto alloc = [&](size_t bytes) { char* r = p; p += (bytes + 255) & ~(size_t)255; return r; };
  u16*   WbB   = (u16*)alloc((size_t)NROWS_PAD * NE * 2);
  u16*   epH   = (u16*)alloc((size_t)ND * NE * 2);
  u16*   epL   = (u16*)alloc((size_t)ND * NE * 2);
  u16*   epTH  = (u16*)alloc((size_t)NE * ND * 2);
  u16*   epTL  = (u16*)alloc((size_t)NE * ND * 2);
  u16*   WpTH  = (u16*)alloc((size_t)DEPTH * NPROJ * ND * 2);
  u16*   WpTL  = (u16*)alloc((size_t)DEPTH * NPROJ * ND * 2);
  u16*   WqTH  = (u16*)alloc((size_t)DEPTH * 3 * ND * NPROJ * 2);
  u16*   WqTL  = (u16*)alloc((size_t)DEPTH * 3 * ND * NPROJ * 2);
  u16*   ExH   = (u16*)alloc((size_t)NTOK * NE * 2);
  u16*   ExL   = (u16*)alloc((size_t)NTOK * NE * 2);
  float* h0    = (float*)alloc((size_t)NTOK * ND * 4);
  float* h1    = (float*)alloc((size_t)NTOK * ND * 4);
  u16*   h0H   = (u16*)alloc((size_t)NTOK * ND * 2);
  u16*   h0L   = (u16*)alloc((size_t)NTOK * ND * 2);
  u16*   h1H   = (u16*)alloc((size_t)NTOK * ND * 2);
  u16*   h1L   = (u16*)alloc((size_t)NTOK * ND * 2);
  u16*   PH    = (u16*)alloc((size_t)NTOK * NPROJ * 2);
  u16*   PL    = (u16*)alloc((size_t)NTOK * NPROJ * 2);
  float* U     = (float*)alloc((size_t)NTOK * 3 * ND * 4);
  float* projh = (float*)alloc((size_t)NTOK * NE * 4);
  u16*   phb   = (u16*)alloc((size_t)NTOK * NE * 2);
  float* accum = (float*)alloc((size_t)NTOK * 6 * 4);

  (void)hipMemsetAsync(accum, 0, (size_t)NTOK * 6 * 4, stream);

  // weight prep (per call; graph-captured)
  conv_hilo<<<256, 256, 0, stream>>>(eproj, epH, epL, (long)ND * NE / 4);
  tconv<<<dim3(NE / 32, ND / 32, 1), 256, 0, stream>>>(eproj, epTH, epTL, ND, NE, 0, 0);
  tconv<<<dim3(NPROJ / 32, ND / 32, DEPTH), 256, 0, stream>>>(
      Wp, WpTH, WpTL, ND, NPROJ, (long)ND * NPROJ, (long)ND * NPROJ);
  tconv<<<dim3(3 * ND / 32, NPROJ / 32, DEPTH), 256, 0, stream>>>(
      Wq, WqTH, WqTL, NPROJ, 3 * ND, (long)NPROJ * 3 * ND, (long)NPROJ * 3 * ND);
  gather_hilo<<<NTOK, NE, 0, stream>>>(x, emb, ExH, ExL);

  // h0 = (emb[x]*32) @ eproj^T
  gemm3<true, true, false><<<dim3(ND / 64, NTOK / 64), 256, 0, stream>>>(
      ExH, ExL, epH, epL, h0, h0H, h0L, nullptr, NTOK, ND, NE);

  float* hcF = h0; u16* hcH = h0H; u16* hcL = h0L;
  float* hnF = h1; u16* hnH = h1H; u16* hnL = h1L;
  for (int l = 0; l < DEPTH; ++l) {
    gemm3<false, true, false><<<dim3(NPROJ / 64, NTOK / 64), 256, 0, stream>>>(
        hcH, hcL, WpTH + (size_t)l * NPROJ * ND, WpTL + (size_t)l * NPROJ * ND,
        nullptr, PH, PL, nullptr, NTOK, NPROJ, ND);
    gemm3<true, false, false><<<dim3(3 * ND / 64, NTOK / 64), 256, 0, stream>>>(
        PH, PL, WqTH + (size_t)l * 3 * ND * NPROJ, WqTL + (size_t)l * 3 * ND * NPROJ,
        U, nullptr, nullptr, nullptr, NTOK, 3 * ND, NPROJ);
    sru_scan<<<16, 256, 0, stream>>>(U, hcF, hidden, wcv, bvec, hnF, hnH, hnL, out, l);
    { float* t = hcF; hcF = hnF; hnF = t; }
    { u16* t = hcH; hcH = hnH; hnH = t; }
    { u16* t = hcL; hcL = hnL; hnL = t; }
  }

  // proj_h = h @ eproj  (fp32 for loss, rne-bf16 for head_tail)
  gemm3<true, false, true><<<dim3(NE / 64, NTOK / 64), 256, 0, stream>>>(
      hcH, hcL, epTH, epTL, projh, nullptr, nullptr, phb, NTOK, NE, ND);

  // emb -> bf16 right before head_tail for L2/L3 residency
  conv_emb<<<2048, 256, 0, stream>>>(emb, cwp, WbB);

  head_tail<<<dim3((NTOK / 128) * (NROWS_PAD / 128)), 256, 0, stream>>>(
      WbB, obias, cbp, phb, accum);

  loss_kernel<<<NTOK, 64, 0, stream>>>(projh, emb, cwp, obias, cbp, y, accum, out);
}